// Round 10
// baseline (2497.823 us; speedup 1.0000x reference)
//
#include <hip/hip_runtime.h>

#define TT 64
#define BB 4096
#define HH 256
#define BM 8              // batch elements per block
#define NBLK (BB / BM)    // 512 blocks -> 2 blocks/CU

// d_ws layout (byte offsets)
#define WS_WHT_B   0u              // W_h^T  f32, 256KB
#define WS_WH2T_B  262144u         // W_h2^T f32, 256KB
#define WS_EMB_B   524288u         // emb f32, 256B
#define WS_REC_B   1048576u        // rec f32 [T,B,4], 4MB

__device__ __forceinline__ float clip01f(float v) {
    return fminf(fmaxf(v, 0.0f), 1.0f);
}

__global__ __launch_bounds__(64) void setup_emb_kernel(float* __restrict__ emb) {
    int i = threadIdx.x;
    const double sigma = 64.0 / 10.0;
    const double c = 32.0;
    double d = ((double)i - c) / sigma;
    double e = exp(-0.5 * (d * d));
    double d0 = (0.0 - c) / sigma;
    double emin = exp(-0.5 * (d0 * d0));
    emb[i] = (float)((e - emin) / (1.0 - emin));   // e.max() = exp(0) = 1
}

__global__ __launch_bounds__(256) void transpose_kernel(const float* __restrict__ src,
                                                        float* __restrict__ dst) {
    __shared__ float tile[32][33];
    int tx = threadIdx.x & 31, ty = threadIdx.x >> 5;
    int bx = blockIdx.x, by = blockIdx.y;
#pragma unroll
    for (int i = 0; i < 32; i += 8)
        tile[ty + i][tx] = src[(by * 32 + ty + i) * HH + bx * 32 + tx];
    __syncthreads();
#pragma unroll
    for (int i = 0; i < 32; i += 8)
        dst[(bx * 32 + ty + i) * HH + by * 32 + tx] = tile[tx][ty + i];
}

// Dense gated matvec: acc[b] = sum_{k=0..255 asc} fmaf(s[k][b], WT[k*256+n], acc[b]).
// s in {1.0f, 0.0f}: fmaf(0,w,a)==a exact, fmaf(1,w,a)==RN(a+w) -> bit-identical
// to the verified active-only ascending chain. Regular counted loop => compiler
// software-pipelines the weight loads (deep vmcnt) and LDS broadcasts.
__device__ __forceinline__ void dense_accum(const float* __restrict__ WT, int n,
                                            const float (*sS)[BM], float acc[BM]) {
    const float* Wp = WT + n;
#pragma unroll 8
    for (int k = 0; k < HH; ++k) {
        float wv = Wp[k << 8];                       // coalesced 256B/wave, L2-resident
        float4 sa = *(const float4*)&sS[k][0];       // same addr all lanes: broadcast
        float4 sb = *(const float4*)&sS[k][4];
        acc[0] = fmaf(sa.x, wv, acc[0]);
        acc[1] = fmaf(sa.y, wv, acc[1]);
        acc[2] = fmaf(sa.z, wv, acc[2]);
        acc[3] = fmaf(sa.w, wv, acc[3]);
        acc[4] = fmaf(sb.x, wv, acc[4]);
        acc[5] = fmaf(sb.y, wv, acc[5]);
        acc[6] = fmaf(sb.z, wv, acc[6]);
        acc[7] = fmaf(sb.w, wv, acc[7]);
    }
}

__global__ __launch_bounds__(256, 2) void snn_main_kernel(
    const float* __restrict__ x,
    const float* __restrict__ W_in, const float* __restrict__ b_in,
    const float* __restrict__ beta_in, const float* __restrict__ thr_in,
    const float* __restrict__ b_h, const float* __restrict__ beta_h, const float* __restrict__ thr_h,
    const float* __restrict__ b_h2, const float* __restrict__ beta_h2, const float* __restrict__ thr_h2,
    const float* __restrict__ W_out, const float* __restrict__ b_out, const float* __restrict__ beta_out,
    const float* __restrict__ WhT, const float* __restrict__ Wh2T,
    const float* __restrict__ emb, float* __restrict__ rec)
{
#pragma clang fp contract(off)   // all contraction EXPLICIT via fmaf below
    const int tid = threadIdx.x;
    const int n = tid;                  // thread = neuron
    const int w = tid >> 6, lane = tid & 63;
    const int b0 = blockIdx.x * BM;

    __shared__ float sS1[HH][BM];            // spike floats layer1 (8KB)
    __shared__ float sS2[HH][BM];            // spike floats layer2 (8KB)
    __shared__ unsigned long long M3L[4][BM];
    __shared__ float WoutS[2][HH];
    WoutS[0][n] = W_out[n];
    WoutS[1][n] = W_out[HH + n];

    float bi  = b_in[n];
    float bt1 = clip01f(beta_in[n]), th1 = thr_in[n];
    float bh  = b_h[n];
    float bt2 = clip01f(beta_h[n]),  th2 = thr_h[n];
    float bh2v = b_h2[n];
    float bt3 = clip01f(beta_h2[n]), th3 = thr_h2[n];
    float wi0 = W_in[n * 3], wi1 = W_in[n * 3 + 1], wi2 = W_in[n * 3 + 2];

    const int ob = (tid >> 1) & (BM - 1);   // output-stage batch (wave 0, tid<2*BM)
    const int oo = tid & 1;                 // output channel
    float bto = clip01f(beta_out[oo]);
    float bo  = b_out[oo];

    float m1[BM], m2[BM], m4[BM], acc[BM];
#pragma unroll
    for (int b = 0; b < BM; ++b) { m1[b] = 0.f; m2[b] = 0.f; m4[b] = 0.f; }
    float m3s = 0.f;

    for (int t = 0; t < TT; ++t) {
        float et = emb[t];
        float xf[BM * 3];
        const float4* xp = (const float4*)(x + (size_t)(t * BB + b0) * 3);
#pragma unroll
        for (int i = 0; i < (BM * 3) / 4; ++i) *(float4*)(xf + 4 * i) = xp[i];

        // ---- layer 1: ascending-k fma dot, bias after; contracted LIF update ----
        {
            float sf[BM];
#pragma unroll
            for (int b = 0; b < BM; ++b) {
                float xe0 = xf[b * 3 + 0] * et;
                float xe1 = xf[b * 3 + 1] * et;
                float xe2 = xf[b * 3 + 2] * et;
                float a1 = xe0 * wi0;                  // == fma(xe0,wi0,0)
                a1 = fmaf(xe1, wi1, a1);
                a1 = fmaf(xe2, wi2, a1);
                float cur = a1 + bi;
                float rf = ((m1[b] - th1) > 0.f) ? 1.f : 0.f;   // reset from PREVIOUS mem
                float mm = fmaf(bt1, m1[b], cur);      // contracted: beta*m + cur
                mm = fmaf(-rf, th1, mm);               // contracted: - reset*thr
                m1[b] = mm;
                sf[b] = ((mm - th1) > 0.f) ? 1.f : 0.f;
            }
            *(float4*)&sS1[n][0] = make_float4(sf[0], sf[1], sf[2], sf[3]);
            *(float4*)&sS1[n][4] = make_float4(sf[4], sf[5], sf[6], sf[7]);
        }
        __syncthreads();

        // ---- layer 2: dense gated fma over sS1 ----
#pragma unroll
        for (int b = 0; b < BM; ++b) acc[b] = 0.f;
        dense_accum(WhT, n, sS1, acc);
        {
            float sf[BM];
#pragma unroll
            for (int b = 0; b < BM; ++b) {
                float cur = acc[b] + bh;
                float rf = ((m2[b] - th2) > 0.f) ? 1.f : 0.f;
                float mm = fmaf(bt2, m2[b], cur);
                mm = fmaf(-rf, th2, mm);
                m2[b] = mm;
                sf[b] = ((mm - th2) > 0.f) ? 1.f : 0.f;
            }
            *(float4*)&sS2[n][0] = make_float4(sf[0], sf[1], sf[2], sf[3]);
            *(float4*)&sS2[n][4] = make_float4(sf[4], sf[5], sf[6], sf[7]);
        }
        __syncthreads();

        // ---- layer 3: dense gated fma over sS2; ballot masks for li_out ----
#pragma unroll
        for (int b = 0; b < BM; ++b) acc[b] = 0.f;
        dense_accum(Wh2T, n, sS2, acc);
        {
            bool s3[BM];
#pragma unroll
            for (int b = 0; b < BM; ++b) {
                float cur = acc[b] + bh2v;
                float rf = ((m4[b] - th3) > 0.f) ? 1.f : 0.f;
                float mm = fmaf(bt3, m4[b], cur);
                mm = fmaf(-rf, th3, mm);
                m4[b] = mm;
                s3[b] = (mm - th3) > 0.f;
            }
#pragma unroll
            for (int b = 0; b < BM; ++b) {
                unsigned long long mk = __ballot(s3[b]);
                if (lane == 0) M3L[w][b] = mk;
            }
        }
        __syncthreads();

        // ---- li_out (verified R8 form): ascending active-only sum;
        //      m3 = fma(beta_out, m3, dot) + b_out ----
        if (w == 0) {
            float p = 0.f;
#pragma unroll
            for (int w2 = 0; w2 < 4; ++w2) {
                unsigned long long mk = M3L[w2][ob];
                const float* wrow = &WoutS[oo][w2 << 6];
                while (mk) {
                    int l = __builtin_ctzll(mk); mk &= mk - 1;
                    p = p + wrow[l];
                }
            }
            float mm3 = fmaf(bto, m3s, p);
            mm3 = mm3 + bo;
            m3s = mm3;
            float spk = ((m3s - 1.0f) > 0.f) ? 1.f : 0.f;
            float om3 = __shfl_xor(m3s, 1, 64);
            float osp = __shfl_xor(spk, 1, 64);
            if (tid < 2 * BM && oo == 0) {         // rec[t, b0+ob, :] = {spk0, spk1, m30, m31}
                *(float4*)(rec + ((size_t)t * BB + b0 + ob) * 4) =
                    make_float4(spk, osp, m3s, om3);
            }
        }
        // other waves proceed to next-t layer1; sS1 rewrite is safe (last read pre-bar2),
        // M3L rewrite happens post-next-bar2, by which wave0 has finished li_out.
    }
}

// out[r,o] = (ascending-k fma dot) + b_pred[o]   (gemm form)
__global__ __launch_bounds__(256) void pred_kernel(
    const float* __restrict__ rec, const float* __restrict__ W_pred,
    const float* __restrict__ b_pred, float* __restrict__ out)
{
#pragma clang fp contract(off)
    int r = blockIdx.x * 256 + threadIdx.x;   // 0..4095
    const float* f = rec + (size_t)r * 256;
    float a0 = 0.f, a1 = 0.f;
#pragma unroll 4
    for (int c = 0; c < 256; ++c) {
        float v = f[c];
        a0 = fmaf(v, W_pred[c], a0);
        a1 = fmaf(v, W_pred[256 + c], a1);
    }
    out[r * 2 + 0] = a0 + b_pred[0];
    out[r * 2 + 1] = a1 + b_pred[1];
}

extern "C" void kernel_launch(void* const* d_in, const int* in_sizes, int n_in,
                              void* d_out, int out_size, void* d_ws, size_t ws_size,
                              hipStream_t stream)
{
    const float* x        = (const float*)d_in[0];
    const float* W_in     = (const float*)d_in[1];
    const float* b_in     = (const float*)d_in[2];
    const float* beta_in  = (const float*)d_in[3];
    const float* thr_in   = (const float*)d_in[4];
    const float* W_h      = (const float*)d_in[5];
    const float* b_h      = (const float*)d_in[6];
    const float* beta_h   = (const float*)d_in[7];
    const float* thr_h    = (const float*)d_in[8];
    const float* W_h2     = (const float*)d_in[9];
    const float* b_h2     = (const float*)d_in[10];
    const float* beta_h2  = (const float*)d_in[11];
    const float* thr_h2   = (const float*)d_in[12];
    const float* W_out    = (const float*)d_in[13];
    const float* b_out    = (const float*)d_in[14];
    const float* beta_out = (const float*)d_in[15];
    const float* W_pred   = (const float*)d_in[16];
    const float* b_pred   = (const float*)d_in[17];

    char* ws = (char*)d_ws;
    float* WhT  = (float*)(ws + WS_WHT_B);
    float* Wh2T = (float*)(ws + WS_WH2T_B);
    float* emb  = (float*)(ws + WS_EMB_B);
    float* rec  = (float*)(ws + WS_REC_B);

    dim3 tgrid(8, 8);
    transpose_kernel<<<tgrid, 256, 0, stream>>>(W_h, WhT);
    transpose_kernel<<<tgrid, 256, 0, stream>>>(W_h2, Wh2T);
    setup_emb_kernel<<<1, 64, 0, stream>>>(emb);

    snn_main_kernel<<<NBLK, 256, 0, stream>>>(
        x, W_in, b_in, beta_in, thr_in,
        b_h, beta_h, thr_h,
        b_h2, beta_h2, thr_h2,
        W_out, b_out, beta_out,
        WhT, Wh2T, emb, rec);

    pred_kernel<<<BB / 256, 256, 0, stream>>>(rec, W_pred, b_pred, (float*)d_out);
}